// Round 8
// baseline (783.990 us; speedup 1.0000x reference)
//
#include <hip/hip_runtime.h>
#include <math.h>

#define NAG 10
#define PP  65536
#define EE  64
#define INW 16
#define NBLK 512
#define NWAVE (NBLK*4)      // 2048 waves -> 8 waves/CU
#define NIT  (PP/NWAVE)     // 32 p's per wave

typedef __attribute__((ext_vector_type(4))) short short4v;
typedef __attribute__((ext_vector_type(4))) float f32x4;

__device__ __forceinline__ short f2bf(float x){
    unsigned u = __float_as_uint(x);
    return (short)((u + 0x8000u) >> 16);     // round-nearest (ties away)
}

#define MFMA16(A,B,C) __builtin_amdgcn_mfma_f32_16x16x16bf16_1k((A),(B),(C),0,0,0)

// Fragment algebra used throughout (verified by rounds 5-7 passing PV step):
//   A-frag(16x16x16): lane holds A[row=l&15][k=(l>>4)*4+j]
//   B-frag:           lane holds B[k=(l>>4)*4+j][col=l&15]
//   D-frag:           lane holds D[row=(l>>4)*4+reg][col=l&15]
//   => a D-frag of M reused as B-operand represents M; as A-operand represents M^T.

__global__ __launch_bounds__(256, 2) void mpnn_reg(
    const float* __restrict__ inp,
    const float* __restrict__ W_enc, const float* __restrict__ b_enc,
    const float* __restrict__ W_goal, const float* __restrict__ b_goal,
    const float* __restrict__ Wq, const float* __restrict__ Wk,
    const float* __restrict__ Wv, const float* __restrict__ Wo,
    const float* __restrict__ W_upd, const float* __restrict__ b_upd,
    float* __restrict__ out)
{
    __shared__ __align__(16) float lds[EE*65];   // init only: WkT, then Wc

    const int tid  = threadIdx.x;
    const int w    = tid >> 6;
    const int l    = tid & 63;
    const int lrow = l & 15;
    const int lk   = l >> 4;

    // ================= init (only place with barriers) =================
    // WkT staging (coalesced read, padded write)
    for (int i = tid; i < EE*EE; i += 256)
        lds[(i & 63)*65 + (i >> 6)] = Wk[i];
    __syncthreads();

    // fqkA[o][i]: A-frag of Wqk^T = (Wq@Wk^T * 1/8)^T
    //   value[j] = Wqk[e_in=16i+lk*4+j][e_out=16o+lrow] * 0.125
    short4v fqkA[4][4];
    #pragma unroll
    for (int i = 0; i < 4; ++i)
      #pragma unroll
      for (int j = 0; j < 4; ++j) {
        const int ein = 16*i + lk*4 + j;
        float s[4] = {0.f,0.f,0.f,0.f};
        for (int t = 0; t < EE; ++t) {
            const float wq = Wq[ein*EE + t];
            #pragma unroll
            for (int o = 0; o < 4; ++o)
                s[o] = fmaf(wq, lds[t*65 + 16*o + lrow], s[o]);
        }
        #pragma unroll
        for (int o = 0; o < 4; ++o)
            fqkA[o][i][j] = f2bf(s[o] * 0.125f);
      }
    __syncthreads();

    // Wc = Wo @ W_upd[64:128]  (both reads coalesced/broadcast)
    for (int i = tid; i < EE*EE; i += 256) {
        const int r = i >> 6, c = i & 63;
        float s = 0.f;
        #pragma unroll 8
        for (int d = 0; d < EE; ++d)
            s = fmaf(Wo[r*EE + d], W_upd[(EE + d)*EE + c], s);
        lds[r*EE + c] = s;
    }
    __syncthreads();

    // fvcB[i][t]: B-frag of Wvc = Wv@Wc ; value[j] = Wvc[16i+lk*4+j][16t+lrow]
    short4v fvcB[4][4];
    #pragma unroll
    for (int i = 0; i < 4; ++i)
      #pragma unroll
      for (int j = 0; j < 4; ++j) {
        const int ein = 16*i + lk*4 + j;
        float s[4] = {0.f,0.f,0.f,0.f};
        for (int d = 0; d < EE; ++d) {
            const float wv = Wv[ein*EE + d];
            #pragma unroll
            for (int t = 0; t < 4; ++t)
                s[t] = fmaf(wv, lds[d*EE + 16*t + lrow], s[t]);
        }
        #pragma unroll
        for (int t = 0; t < 4; ++t)
            fvcB[i][t][j] = f2bf(s[t]);
      }
    // LDS dead from here; no further barriers.

    // fencA[i]: A-frag of Wenc^T (rows d>=14 zero)
    short4v fencA[4];
    #pragma unroll
    for (int i = 0; i < 4; ++i)
      #pragma unroll
      for (int j = 0; j < 4; ++j) {
        const int d = lk*4 + j;
        fencA[i][j] = (d < 14) ? f2bf(W_enc[d*EE + 16*i + lrow]) : (short)0;
      }
    // fuwB[i][t]: B-frag of W_upd top half
    short4v fuwB[4][4];
    #pragma unroll
    for (int i = 0; i < 4; ++i)
      #pragma unroll
      for (int t = 0; t < 4; ++t)
        #pragma unroll
        for (int j = 0; j < 4; ++j)
          fuwB[i][t][j] = f2bf(W_upd[(16*i + lk*4 + j)*EE + 16*t + lrow]);

    // per-lane bias / goal-weight vectors
    float benc16[16];
    #pragma unroll
    for (int i = 0; i < 4; ++i)
      #pragma unroll
      for (int r = 0; r < 4; ++r)
        benc16[i*4 + r] = b_enc[16*i + lk*4 + r];
    float bupd4[4], wg0v[4], wg1v[4], bgv[4];
    #pragma unroll
    for (int t = 0; t < 4; ++t) {
        bupd4[t] = b_upd[16*t + lrow];
        wg0v[t]  = W_goal[16*t + lrow];
        wg1v[t]  = W_goal[EE + 16*t + lrow];
        bgv[t]   = b_goal[16*t + lrow];
    }

    // ================= main loop: one wave = one p, zero LDS/barriers =================
    const int gwave = blockIdx.x*4 + w;
    const int arow  = (lrow < NAG) ? lrow : 0;   // clamp pad-agents to agent 0 (valid reads)
    const float* xptr = inp + (size_t)arow*PP*INW + lk*4;

    f32x4 xin = *(const f32x4*)(xptr + (size_t)gwave*INW);

    for (int it = 0; it < NIT; ++it) {
        const int p = gwave + it*NWAVE;
        const f32x4 xcur = xin;
        if (it + 1 < NIT)
            xin = *(const f32x4*)(xptr + (size_t)(p + NWAVE)*INW);

        // goal scalars live in lane 48 (lk=3,lrow=0: X[0][12..15]), elems 2,3
        const float g0 = __shfl(xcur[2], 48, 64);
        const float g1 = __shfl(xcur[3], 48, 64);

        // X as B-frag of X^T: lane holds X[agent=lrow][d=lk*4+j]
        short4v xb;
        #pragma unroll
        for (int j = 0; j < 4; ++j) xb[j] = f2bf(xcur[j]);

        // ---- h^T slices: hT[i] = relu(Wenc^T @ X^T + b)   (D[row=e-local][col=agent])
        f32x4 hT[4];
        #pragma unroll
        for (int i = 0; i < 4; ++i) {
            f32x4 zz = {0.f,0.f,0.f,0.f};
            hT[i] = MFMA16(fencA[i], xb, zz);
            #pragma unroll
            for (int r = 0; r < 4; ++r)
                hT[i][r] = fmaxf(hT[i][r] + benc16[i*4 + r], 0.f);
        }

        // ---- h0[e]=h[agent0][e] at positions e=16t+lrow  (shfl from col-0 lanes)
        const int src = (lrow >> 2) * 16;
        float h0v[4], h2v[4];
        #pragma unroll
        for (int t = 0; t < 4; ++t) {
            const float s0 = __shfl(hT[t][0], src, 64);
            const float s1 = __shfl(hT[t][1], src, 64);
            const float s2 = __shfl(hT[t][2], src, 64);
            const float s3 = __shfl(hT[t][3], src, 64);
            const float lo = (lrow & 2) ? s2 : s0;
            const float hi = (lrow & 2) ? s3 : s1;
            h0v[t] = (lrow & 1) ? hi : lo;
            h2v[t] = fmaxf(fmaf(g0, wg0v[t], fmaf(g1, wg1v[t], bgv[t])), 0.f);
        }

        // bf16 h fragments (D-frags of h^T slices)
        short4v hb[4];
        #pragma unroll
        for (int i = 0; i < 4; ++i)
            #pragma unroll
            for (int j = 0; j < 4; ++j) hb[i][j] = f2bf(hT[i][j]);

        // ---- G^T slices: gT[o] = sum_i Wqk^T[o][i] @ h^T[i]
        short4v gb[4];
        #pragma unroll
        for (int o = 0; o < 4; ++o) {
            f32x4 acc = {0.f,0.f,0.f,0.f};
            #pragma unroll
            for (int i = 0; i < 4; ++i)
                acc = MFMA16(fqkA[o][i], hb[i], acc);
            #pragma unroll
            for (int j = 0; j < 4; ++j) gb[o][j] = f2bf(acc[j]);
        }

        // ---- S^T = sum_i mfma(A=hb[i] (as h), B=gb[i] (as G^T)):
        //      lane holds S^T[k=lk*4+j][q=lrow]  (scale folded in Wqk)
        f32x4 st = {0.f,0.f,0.f,0.f};
        #pragma unroll
        for (int i = 0; i < 4; ++i)
            st = MFMA16(hb[i], gb[i], st);

        // ---- masked softmax over k (in-lane 4 + xor16/32), identical to prior rounds
        float c4[4]; float mx4 = -1e30f;
        #pragma unroll
        for (int j = 0; j < 4; ++j) {
            const int k = lk*4 + j;
            const bool valid = (lrow < NAG) && (k < NAG) && (k != lrow) && (k != 0);
            c4[j] = valid ? st[j] : -1e30f;
            mx4 = fmaxf(mx4, c4[j]);
        }
        float mx = fmaxf(mx4, __shfl_xor(mx4, 16, 64));
        mx = fmaxf(mx, __shfl_xor(mx, 32, 64));
        float e4[4], ssum = 0.f;
        #pragma unroll
        for (int j = 0; j < 4; ++j) { e4[j] = __expf(c4[j] - mx); ssum += e4[j]; }
        ssum += __shfl_xor(ssum, 16, 64);
        ssum += __shfl_xor(ssum, 32, 64);
        const float inv = 1.f / ssum;
        short4v pa;                         // A-frag of P (row=q, k=agent)
        #pragma unroll
        for (int j = 0; j < 4; ++j) pa[j] = f2bf(e4[j] * inv);

        // ---- Z = h @ Wvc   (D[row=agent][col=e-tile]; D-as-B feeds PV directly)
        short4v zbv[4];
        #pragma unroll
        for (int t = 0; t < 4; ++t) {
            f32x4 acc = {0.f,0.f,0.f,0.f};
            #pragma unroll
            for (int i = 0; i < 4; ++i)
                acc = MFMA16(hb[i], fvcB[i][t], acc);
            #pragma unroll
            for (int j = 0; j < 4; ++j) zbv[t][j] = f2bf(acc[j]);
        }

        // ---- u = relu(P@Z + h@Wu_top + b_upd), fused store epilogue
        #pragma unroll
        for (int t = 0; t < 4; ++t) {
            f32x4 acc = {0.f,0.f,0.f,0.f};
            acc = MFMA16(pa, zbv[t], acc);
            #pragma unroll
            for (int i = 0; i < 4; ++i)
                acc = MFMA16(hb[i], fuwB[i][t], acc);
            #pragma unroll
            for (int r = 0; r < 4; ++r) {
                const int agent = lk*4 + r;
                if (agent < NAG) {
                    const float uu = fmaxf(acc[r] + bupd4[t], 0.f);
                    // unified row index: leader (agent 0) -> p ; follower a -> a*PP + p
                    const size_t row = (size_t)agent*PP + (size_t)p;
                    float* dst = out + row*128 + 16*t + lrow;
                    __builtin_nontemporal_store(uu, dst);
                    const float hh = agent ? h0v[t] : h2v[t];
                    __builtin_nontemporal_store(hh, dst + 64);
                }
            }
        }
    }
}

extern "C" void kernel_launch(void* const* d_in, const int* in_sizes, int n_in,
                              void* d_out, int out_size, void* d_ws, size_t ws_size,
                              hipStream_t stream) {
    const float* inp    = (const float*)d_in[0];
    const float* W_enc  = (const float*)d_in[1];
    const float* b_enc  = (const float*)d_in[2];
    const float* W_goal = (const float*)d_in[3];
    const float* b_goal = (const float*)d_in[4];
    const float* Wq     = (const float*)d_in[5];
    const float* Wk     = (const float*)d_in[6];
    const float* Wv     = (const float*)d_in[7];
    const float* Wo     = (const float*)d_in[8];
    const float* W_upd  = (const float*)d_in[9];
    const float* b_upd  = (const float*)d_in[10];

    hipLaunchKernelGGL(mpnn_reg, dim3(NBLK), dim3(256), 0, stream,
                       inp, W_enc, b_enc, W_goal, b_goal,
                       Wq, Wk, Wv, Wo, W_upd, b_upd, (float*)d_out);
}

// Round 9
// 411.794 us; speedup vs baseline: 1.9038x; 1.9038x over previous
//
#include <hip/hip_runtime.h>
#include <math.h>

#define NAG 10
#define PP  65536
#define EE  64
#define INW 16
#define NBLK 512
#define NWAVE (NBLK*4)      // 2048 waves -> 8 waves/CU
#define NIT  (PP/NWAVE)     // 32 p's per wave
#define SROW 132            // f32 stride of u staging rows
#define WLDS (NAG*SROW + 2*64)   // per-wave staging floats (u tile + h2 row + h0 row)

typedef __attribute__((ext_vector_type(4))) short short4v;
typedef __attribute__((ext_vector_type(4))) float f32x4;

__device__ __forceinline__ short f2bf(float x){
    unsigned u = __float_as_uint(x);
    return (short)((u + 0x8000u) >> 16);     // round-nearest (ties away)
}

#define MFMA16(A,B,C) __builtin_amdgcn_mfma_f32_16x16x16bf16_1k((A),(B),(C),0,0,0)

// Fragment algebra (HW-verified by rounds 5-8 passing):
//   A-frag(16x16x16): lane holds A[row=l&15][k=(l>>4)*4+j]
//   B-frag:           lane holds B[k=(l>>4)*4+j][col=l&15]
//   D-frag:           lane holds D[row=(l>>4)*4+reg][col=l&15]
//   => a D-frag of M reused as B-operand represents M; as A-operand represents M^T.

__global__ __launch_bounds__(256, 2) void mpnn_reg2(
    const float* __restrict__ inp,
    const float* __restrict__ W_enc, const float* __restrict__ b_enc,
    const float* __restrict__ W_goal, const float* __restrict__ b_goal,
    const float* __restrict__ Wq, const float* __restrict__ Wk,
    const float* __restrict__ Wv, const float* __restrict__ Wo,
    const float* __restrict__ W_upd, const float* __restrict__ b_upd,
    float* __restrict__ out)
{
    // init: weight-fold scratch (needs 64*65 f32 = 16.6 KB -> fits in stile)
    // main: per-wave output staging, no cross-wave sharing -> no barriers
    __shared__ __align__(16) float stile[4*WLDS];   // 4*1448*4 = 23168 B

    const int tid  = threadIdx.x;
    const int w    = tid >> 6;
    const int l    = tid & 63;
    const int lrow = l & 15;
    const int lk   = l >> 4;

    float* const lds = stile;                 // init-phase alias (16.9 KB used)
    float* const us  = &stile[w*WLDS];        // u tile [NAG][SROW]
    float* const h2r = us + NAG*SROW;         // 64 floats
    float* const h0r = h2r + 64;              // 64 floats

    // ================= init (only place with barriers) =================
    for (int i = tid; i < EE*EE; i += 256)
        lds[(i & 63)*65 + (i >> 6)] = Wk[i];
    __syncthreads();

    // fqkA[o][i]: A-frag of Wqk^T = (Wq@Wk^T * 1/8)^T
    short4v fqkA[4][4];
    #pragma unroll
    for (int i = 0; i < 4; ++i)
      #pragma unroll
      for (int j = 0; j < 4; ++j) {
        const int ein = 16*i + lk*4 + j;
        float s[4] = {0.f,0.f,0.f,0.f};
        for (int t = 0; t < EE; ++t) {
            const float wq = Wq[ein*EE + t];
            #pragma unroll
            for (int o = 0; o < 4; ++o)
                s[o] = fmaf(wq, lds[t*65 + 16*o + lrow], s[o]);
        }
        #pragma unroll
        for (int o = 0; o < 4; ++o)
            fqkA[o][i][j] = f2bf(s[o] * 0.125f);
      }
    __syncthreads();

    // Wc = Wo @ W_upd[64:128]
    for (int i = tid; i < EE*EE; i += 256) {
        const int r = i >> 6, c = i & 63;
        float s = 0.f;
        #pragma unroll 8
        for (int d = 0; d < EE; ++d)
            s = fmaf(Wo[r*EE + d], W_upd[(EE + d)*EE + c], s);
        lds[r*EE + c] = s;
    }
    __syncthreads();

    // fvcB[i][t]: B-frag of Wvc = Wv@Wc
    short4v fvcB[4][4];
    #pragma unroll
    for (int i = 0; i < 4; ++i)
      #pragma unroll
      for (int j = 0; j < 4; ++j) {
        const int ein = 16*i + lk*4 + j;
        float s[4] = {0.f,0.f,0.f,0.f};
        for (int d = 0; d < EE; ++d) {
            const float wv = Wv[ein*EE + d];
            #pragma unroll
            for (int t = 0; t < 4; ++t)
                s[t] = fmaf(wv, lds[d*EE + 16*t + lrow], s[t]);
        }
        #pragma unroll
        for (int t = 0; t < 4; ++t)
            fvcB[i][t][j] = f2bf(s[t]);
      }
    __syncthreads();   // lds free -> per-wave staging from here (wave-local only)

    // fencA[i]: A-frag of Wenc^T (rows d>=14 zero)
    short4v fencA[4];
    #pragma unroll
    for (int i = 0; i < 4; ++i)
      #pragma unroll
      for (int j = 0; j < 4; ++j) {
        const int d = lk*4 + j;
        fencA[i][j] = (d < 14) ? f2bf(W_enc[d*EE + 16*i + lrow]) : (short)0;
      }
    // fuwB[i][t]: B-frag of W_upd top half
    short4v fuwB[4][4];
    #pragma unroll
    for (int i = 0; i < 4; ++i)
      #pragma unroll
      for (int t = 0; t < 4; ++t)
        #pragma unroll
        for (int j = 0; j < 4; ++j)
          fuwB[i][t][j] = f2bf(W_upd[(16*i + lk*4 + j)*EE + 16*t + lrow]);

    float benc16[16];
    #pragma unroll
    for (int i = 0; i < 4; ++i)
      #pragma unroll
      for (int r = 0; r < 4; ++r)
        benc16[i*4 + r] = b_enc[16*i + lk*4 + r];
    float bupd4[4], wg0v[4], wg1v[4], bgv[4];
    #pragma unroll
    for (int t = 0; t < 4; ++t) {
        bupd4[t] = b_upd[16*t + lrow];
        wg0v[t]  = W_goal[16*t + lrow];
        wg1v[t]  = W_goal[EE + 16*t + lrow];
        bgv[t]   = b_goal[16*t + lrow];
    }

    // ================= main loop: one wave = one p =================
    const int gwave = blockIdx.x*4 + w;
    const int arow  = (lrow < NAG) ? lrow : 0;   // clamp pad-agents (valid reads)
    const float* xptr = inp + (size_t)arow*PP*INW + lk*4;

    f32x4 xin = *(const f32x4*)(xptr + (size_t)gwave*INW);

    for (int it = 0; it < NIT; ++it) {
        const int p = gwave + it*NWAVE;
        const f32x4 xcur = xin;
        if (it + 1 < NIT)
            xin = *(const f32x4*)(xptr + (size_t)(p + NWAVE)*INW);

        // goal scalars live in lane 48 (lk=3,lrow=0: X[0][12..15]), elems 2,3
        const float g0 = __shfl(xcur[2], 48, 64);
        const float g1 = __shfl(xcur[3], 48, 64);

        short4v xb;     // B-frag of X^T
        #pragma unroll
        for (int j = 0; j < 4; ++j) xb[j] = f2bf(xcur[j]);

        // ---- h^T slices
        f32x4 hT[4];
        #pragma unroll
        for (int i = 0; i < 4; ++i) {
            f32x4 zz = {0.f,0.f,0.f,0.f};
            hT[i] = MFMA16(fencA[i], xb, zz);
            #pragma unroll
            for (int r = 0; r < 4; ++r)
                hT[i][r] = fmaxf(hT[i][r] + benc16[i*4 + r], 0.f);
        }

        // h0[e], h2[e] at e = 16t+lrow
        const int src = (lrow >> 2) * 16;
        float h0v[4], h2v[4];
        #pragma unroll
        for (int t = 0; t < 4; ++t) {
            const float s0 = __shfl(hT[t][0], src, 64);
            const float s1 = __shfl(hT[t][1], src, 64);
            const float s2 = __shfl(hT[t][2], src, 64);
            const float s3 = __shfl(hT[t][3], src, 64);
            const float lo = (lrow & 2) ? s2 : s0;
            const float hi = (lrow & 2) ? s3 : s1;
            h0v[t] = (lrow & 1) ? hi : lo;
            h2v[t] = fmaxf(fmaf(g0, wg0v[t], fmaf(g1, wg1v[t], bgv[t])), 0.f);
        }

        short4v hb[4];
        #pragma unroll
        for (int i = 0; i < 4; ++i)
            #pragma unroll
            for (int j = 0; j < 4; ++j) hb[i][j] = f2bf(hT[i][j]);

        // ---- G^T slices
        short4v gb[4];
        #pragma unroll
        for (int o = 0; o < 4; ++o) {
            f32x4 acc = {0.f,0.f,0.f,0.f};
            #pragma unroll
            for (int i = 0; i < 4; ++i)
                acc = MFMA16(fqkA[o][i], hb[i], acc);
            #pragma unroll
            for (int j = 0; j < 4; ++j) gb[o][j] = f2bf(acc[j]);
        }

        // ---- S^T; lane holds S^T[k=lk*4+j][q=lrow]
        f32x4 st = {0.f,0.f,0.f,0.f};
        #pragma unroll
        for (int i = 0; i < 4; ++i)
            st = MFMA16(hb[i], gb[i], st);

        // ---- masked softmax
        float c4[4]; float mx4 = -1e30f;
        #pragma unroll
        for (int j = 0; j < 4; ++j) {
            const int k = lk*4 + j;
            const bool valid = (lrow < NAG) && (k < NAG) && (k != lrow) && (k != 0);
            c4[j] = valid ? st[j] : -1e30f;
            mx4 = fmaxf(mx4, c4[j]);
        }
        float mx = fmaxf(mx4, __shfl_xor(mx4, 16, 64));
        mx = fmaxf(mx, __shfl_xor(mx, 32, 64));
        float e4[4], ssum = 0.f;
        #pragma unroll
        for (int j = 0; j < 4; ++j) { e4[j] = __expf(c4[j] - mx); ssum += e4[j]; }
        ssum += __shfl_xor(ssum, 16, 64);
        ssum += __shfl_xor(ssum, 32, 64);
        const float inv = 1.f / ssum;
        short4v pa;
        #pragma unroll
        for (int j = 0; j < 4; ++j) pa[j] = f2bf(e4[j] * inv);

        // ---- Z = h @ Wvc
        short4v zbv[4];
        #pragma unroll
        for (int t = 0; t < 4; ++t) {
            f32x4 acc = {0.f,0.f,0.f,0.f};
            #pragma unroll
            for (int i = 0; i < 4; ++i)
                acc = MFMA16(hb[i], fvcB[i][t], acc);
            #pragma unroll
            for (int j = 0; j < 4; ++j) zbv[t][j] = f2bf(acc[j]);
        }

        // ---- u = relu(P@Z + h@Wu_top + b_upd) -> per-wave LDS staging
        #pragma unroll
        for (int t = 0; t < 4; ++t) {
            f32x4 acc = {0.f,0.f,0.f,0.f};
            acc = MFMA16(pa, zbv[t], acc);
            #pragma unroll
            for (int i = 0; i < 4; ++i)
                acc = MFMA16(hb[i], fuwB[i][t], acc);
            #pragma unroll
            for (int r = 0; r < 4; ++r) {
                const int agent = lk*4 + r;
                if (agent < NAG)
                    us[agent*SROW + 16*t + lrow] = fmaxf(acc[r] + bupd4[t], 0.f);
            }
        }
        if (lk == 0) {      // h rows: value depends only on lrow,t -> one writer
            #pragma unroll
            for (int t = 0; t < 4; ++t) {
                h2r[16*t + lrow] = h2v[t];
                h0r[16*t + lrow] = h0v[t];
            }
        }
        // wave-internal ds_write -> ds_read: in-order per wave (lgkmcnt auto)

        // ---- coalesced full-line nt stores: 10 rows x 512 B
        #pragma unroll
        for (int c = 0; c < 5; ++c) {
            const int flat = c*64 + l;
            const int row  = flat >> 5;          // 0..9 (agent)
            const int c4i  = flat & 31;          // float4 index within 128 cols
            const float* sp = (c4i < 16)
                ? &us[row*SROW + c4i*4]
                : ((row == 0) ? &h2r[(c4i-16)*4] : &h0r[(c4i-16)*4]);
            const f32x4 v = *reinterpret_cast<const f32x4*>(sp);
            float* dst = out + ((size_t)row*PP + (size_t)p)*128 + c4i*4;
            __builtin_nontemporal_store(v, (f32x4*)dst);
        }
    }
}

extern "C" void kernel_launch(void* const* d_in, const int* in_sizes, int n_in,
                              void* d_out, int out_size, void* d_ws, size_t ws_size,
                              hipStream_t stream) {
    const float* inp    = (const float*)d_in[0];
    const float* W_enc  = (const float*)d_in[1];
    const float* b_enc  = (const float*)d_in[2];
    const float* W_goal = (const float*)d_in[3];
    const float* b_goal = (const float*)d_in[4];
    const float* Wq     = (const float*)d_in[5];
    const float* Wk     = (const float*)d_in[6];
    const float* Wv     = (const float*)d_in[7];
    const float* Wo     = (const float*)d_in[8];
    const float* W_upd  = (const float*)d_in[9];
    const float* b_upd  = (const float*)d_in[10];

    hipLaunchKernelGGL(mpnn_reg2, dim3(NBLK), dim3(256), 0, stream,
                       inp, W_enc, b_enc, W_goal, b_goal,
                       Wq, Wk, Wv, Wo, W_upd, b_upd, (float*)d_out);
}